// Round 2
// baseline (477.341 us; speedup 1.0000x reference)
//
#include <hip/hip_runtime.h>

#define L2E 1.44269504088896340736f
#define INV_SCALE 0.08838834764831845f  // 1/sqrt(128)

typedef _Float16 half8 __attribute__((ext_vector_type(8)));
typedef _Float16 half4 __attribute__((ext_vector_type(4)));
typedef float f32x4 __attribute__((ext_vector_type(4)));

__device__ __forceinline__ float exp2_fast(float x) {
#if __has_builtin(__builtin_amdgcn_exp2f)
  return __builtin_amdgcn_exp2f(x);
#else
  return exp2f(x);
#endif
}

__device__ __forceinline__ f32x4 mfma16(half8 a, half8 b, f32x4 c) {
  return __builtin_amdgcn_mfma_f32_16x16x32_f16(a, b, c, 0, 0, 0);
}

__device__ __forceinline__ void gload16(const void* g, void* l) {
  __builtin_amdgcn_global_load_lds(
      (const __attribute__((address_space(1))) void*)g,
      (__attribute__((address_space(3))) void*)l, 16, 0, 0);
}

__device__ __forceinline__ float swish_f(float v) {
  return v / (1.f + exp2_fast(-L2E * v));
}

template <int CTRL>
__device__ __forceinline__ float dppmov(float x) {
  int xi = __builtin_bit_cast(int, x);
  int r = __builtin_amdgcn_update_dpp(xi, xi, CTRL, 0xf, 0xf, false);
  return __builtin_bit_cast(float, r);
}
__device__ __forceinline__ float red16_sum(float x) {
  x += dppmov<0xB1>(x);
  x += dppmov<0x4E>(x);
  x += dppmov<0x141>(x);
  x += dppmov<0x140>(x);
  return x;
}

// ---------------------------------------------------------------------------
// prep: f16 B-fragment images of the 5 weight matrices.
// ---------------------------------------------------------------------------
__global__ __launch_bounds__(256) void prep_kernel(
    const float* __restrict__ Wq, const float* __restrict__ Wk,
    const float* __restrict__ Wv, const float* __restrict__ W1,
    const float* __restrict__ W2, _Float16* __restrict__ Wf) {
  const int g = blockIdx.x * 256 + threadIdx.x;  // [0, 10240)
  const int mat = g >> 11, rem = g & 2047;
  const int f = rem >> 6, lane = rem & 63;
  const int n = (f >> 2) * 16 + (lane & 15);
  const int k0 = (f & 3) * 32 + (lane >> 4) * 8;
  const float* W = (mat == 0) ? Wq : (mat == 1) ? Wk : (mat == 2) ? Wv
                   : (mat == 3) ? W1 : W2;
  half8 h;
#pragma unroll
  for (int j = 0; j < 8; ++j) h[j] = (_Float16)W[(k0 + j) * 128 + n];
  *(half8*)(Wf + (size_t)g * 8) = h;
}

// ---------------------------------------------------------------------------
// kv: K/V projections into MFMA-fragment-ordered global images.
// ---------------------------------------------------------------------------
__global__ __launch_bounds__(256) void kv_kernel(
    const float* __restrict__ x, const _Float16* __restrict__ Wf,
    _Float16* __restrict__ Kg, _Float16* __restrict__ Vg) {
  __shared__ __align__(16) _Float16 sc[64 * 136];
  const int tid = threadIdx.x;
  const int w = tid >> 6, lane = tid & 63;
  const int n16 = lane & 15, quad = lane >> 4;
  const int blk = blockIdx.x;  // 64 rows/block

  half8 xf[4];
  {
    const float* xr = x + (size_t)(blk * 64 + w * 16 + n16) * 128 + quad * 8;
#pragma unroll
    for (int kc = 0; kc < 4; ++kc) {
      float4 a = *(const float4*)(xr + kc * 32);
      float4 b = *(const float4*)(xr + kc * 32 + 4);
      half8 h;
      h[0] = (_Float16)a.x; h[1] = (_Float16)a.y;
      h[2] = (_Float16)a.z; h[3] = (_Float16)a.w;
      h[4] = (_Float16)b.x; h[5] = (_Float16)b.y;
      h[6] = (_Float16)b.z; h[7] = (_Float16)b.w;
      xf[kc] = h;
    }
  }

  for (int mat = 0; mat < 2; ++mat) {  // 0 -> Wk image(1), 1 -> Wv image(2)
    f32x4 acc[8];
#pragma unroll
    for (int ct = 0; ct < 8; ++ct) acc[ct] = f32x4{0.f, 0.f, 0.f, 0.f};
#pragma unroll
    for (int ct = 0; ct < 8; ++ct)
#pragma unroll
      for (int kc = 0; kc < 4; ++kc) {
        half8 wf = *(const half8*)(Wf +
            ((size_t)((mat + 1) * 32 + ct * 4 + kc) * 64 + lane) * 8);
        acc[ct] = mfma16(xf[kc], wf, acc[ct]);
      }
#pragma unroll
    for (int ct = 0; ct < 8; ++ct)
#pragma unroll
      for (int r = 0; r < 4; ++r)
        sc[(w * 16 + quad * 4 + r) * 136 + ct * 16 + n16] = (_Float16)acc[ct][r];
    __syncthreads();

    if (mat == 0) {  // K
#pragma unroll
      for (int i = 0; i < 4; ++i) {
        const int c = tid + 256 * i;
        const int ln = c & 63, kc = (c >> 6) & 3, ct = (c >> 8) & 1, tl = (c >> 9) & 1;
        half8 v = *(const half8*)&sc[(tl * 32 + ct * 16 + (ln & 15)) * 136 +
                                     kc * 32 + (ln >> 4) * 8];
        *(half8*)(Kg + ((((size_t)(blk * 2 + tl)) * 2 + ct) * 4 + kc) * 512 + ln * 8) = v;
      }
    } else {  // V transposed fragments
#pragma unroll
      for (int i = 0; i < 4; ++i) {
        const int c = tid + 256 * i;
        const int ln = c & 63, dt = (c >> 6) & 7, tl = (c >> 9) & 1;
        const int q2 = ln >> 4, nn = ln & 15;
        half8 v;
#pragma unroll
        for (int j = 0; j < 8; ++j)
          v[j] = sc[(tl * 32 + q2 * 8 + j) * 136 + dt * 16 + nn];
        *(half8*)(Vg + (((size_t)(blk * 2 + tl)) * 8 + dt) * 512 + ln * 8) = v;
      }
    }
    __syncthreads();
  }
}

// ---------------------------------------------------------------------------
// flash: S^T = K.Q^T layout, online softmax in registers.
//
// R2 change (T3/T4): replace __syncthreads() (which drains vmcnt(0), exposing
// the conn HBM latency at EVERY barrier) with raw s_barrier + counted
// s_waitcnt vmcnt(PP). Prefetch depth 2 phases: stage(t+2)/conn(t+2) stay in
// flight across the phase-t barrier. T5 setprio around MFMA clusters.
// ---------------------------------------------------------------------------
template <int NW>
__global__ __launch_bounds__(NW * 64) void flash_kernel(
    const float* __restrict__ x, const float* __restrict__ conn,
    const _Float16* __restrict__ Wf,
    const _Float16* __restrict__ Kg, const _Float16* __restrict__ Vg,
    _Float16* __restrict__ Og, float2* __restrict__ Ml,
    int nsplit, int nt) {
  __shared__ __align__(16) _Float16 kb[2][4096];
  __shared__ __align__(16) _Float16 vb[2][4096];
  __shared__ __align__(16) _Float16 pb[NW][656];
  __shared__ __align__(16) float alb[NW][16];

  const int tid = threadIdx.x, w = tid >> 6, lane = tid & 63;
  const int n16 = lane & 15, quad = lane >> 4;
  const int bid = blockIdx.x;
  int batch, sk, rg;
  if (nsplit == 4) {
    batch = bid & 3; sk = (bid >> 2) & 3; rg = bid >> 4;
  } else if (nsplit == 2) {
    batch = bid & 3; sk = (bid >> 2) & 1; rg = bid >> 3;
  } else {
    batch = bid & 3; sk = 0; rg = bid >> 2;
  }
  const int rt_g = batch * 256 + rg * NW + w;
  const int t0 = sk * nt;
  const int rowb = rg * (NW * 16) + w * 16 + n16;  // q-row within batch

  // per-wave private scratch region (2176 f16 needed, buffers are 4096)
  _Float16* scratch = (w < 2) ? &kb[w][0] : &vb[w - 2][0];

  // ---- Q = x @ Wq for this wave's 16 rows (once); scratch in kb/vb ----
  half8 qf[4];
  {
    half8 xf[4];
    const float* xr = x + ((size_t)batch * 4096 + rowb) * 128 + quad * 8;
#pragma unroll
    for (int kc = 0; kc < 4; ++kc) {
      float4 a = *(const float4*)(xr + kc * 32);
      float4 b = *(const float4*)(xr + kc * 32 + 4);
      half8 h;
      h[0] = (_Float16)a.x; h[1] = (_Float16)a.y;
      h[2] = (_Float16)a.z; h[3] = (_Float16)a.w;
      h[4] = (_Float16)b.x; h[5] = (_Float16)b.y;
      h[6] = (_Float16)b.z; h[7] = (_Float16)b.w;
      xf[kc] = h;
    }
    _Float16* tw = scratch;
#pragma unroll
    for (int ct = 0; ct < 8; ++ct) {
      f32x4 aq = f32x4{0.f, 0.f, 0.f, 0.f};
#pragma unroll
      for (int kc = 0; kc < 4; ++kc) {
        half8 wf = *(const half8*)(Wf + ((size_t)(ct * 4 + kc) * 64 + lane) * 8);
        aq = mfma16(xf[kc], wf, aq);
      }
#pragma unroll
      for (int r = 0; r < 4; ++r)
        tw[(quad * 4 + r) * 136 + ct * 16 + n16] = (_Float16)aq[r];
    }
#pragma unroll
    for (int kc = 0; kc < 4; ++kc)
      qf[kc] = *(const half8*)(tw + n16 * 136 + kc * 32 + quad * 8);
  }
  __syncthreads();  // scratch reads drained; kb/vb free for staging

  const _Float16* kp = Kg + (size_t)batch * 524288 + (size_t)t0 * 4096 + tid * 8;
  const _Float16* vp = Vg + (size_t)batch * 524288 + (size_t)t0 * 4096 + tid * 8;
  const float* cp = conn + (size_t)batch * 16777216 + (size_t)rowb * 4096 +
                    (size_t)t0 * 32 + quad * 4;
  const int wbase = (tid & ~63) * 8;
  constexpr int NC = 8 / NW;      // gload16 per matrix per thread
  constexpr int PP = 2 * NC + 2;  // VMEM ops issued per phase (stage + conn)

  auto stage = [&](int t, int buf) {
    const _Float16* ks = kp + (size_t)t * 4096;
    const _Float16* vs = vp + (size_t)t * 4096;
#pragma unroll
    for (int c = 0; c < NC; ++c) {
      gload16(ks + c * (NW * 512), &kb[buf][c * (NW * 512) + wbase]);
      gload16(vs + c * (NW * 512), &vb[buf][c * (NW * 512) + wbase]);
    }
  };
  auto ldconn = [&](int i, float4* cr) {
    const float* c0 = cp + (size_t)i * 32;
    cr[0] = *(const float4*)c0;
    cr[1] = *(const float4*)(c0 + 16);
  };

  f32x4 o[8];
#pragma unroll
  for (int dt = 0; dt < 8; ++dt) o[dt] = f32x4{0.f, 0.f, 0.f, 0.f};
  float m_i = -__builtin_inff();
  float l_i = 0.f;

  auto compute = [&](int buf, const float4* cc) {
    f32x4 s0 = f32x4{0.f, 0.f, 0.f, 0.f};
    f32x4 s1 = f32x4{0.f, 0.f, 0.f, 0.f};
    const _Float16* kc_ = kb[buf];
    __builtin_amdgcn_s_setprio(1);
#pragma unroll
    for (int kc = 0; kc < 4; ++kc) {
      half8 kf0 = *(const half8*)&kc_[kc * 512 + lane * 8];
      half8 kf1 = *(const half8*)&kc_[(4 + kc) * 512 + lane * 8];
      s0 = mfma16(kf0, qf[kc], s0);  // S^T: A=K, B=Q
      s1 = mfma16(kf1, qf[kc], s1);
    }
    __builtin_amdgcn_s_setprio(0);
    float pr[8];
#pragma unroll
    for (int r = 0; r < 4; ++r) {
      pr[r] = fmaf(s0[r], INV_SCALE, cc[0][r]);
      pr[4 + r] = fmaf(s1[r], INV_SCALE, cc[1][r]);
    }
    float mx = pr[0];
#pragma unroll
    for (int c = 1; c < 8; ++c) mx = fmaxf(mx, pr[c]);
    mx = fmaxf(mx, __shfl_xor(mx, 16, 64));
    mx = fmaxf(mx, __shfl_xor(mx, 32, 64));
    if (__any(mx > m_i)) {
      const float mn = fmaxf(m_i, mx);
      const float al = exp2_fast((m_i - mn) * L2E);
      m_i = mn;
      l_i *= al;
      if (quad == 0) alb[w][n16] = al;
      const float4 av = *(const float4*)&alb[w][quad * 4];
#pragma unroll
      for (int dt = 0; dt < 8; ++dt)
#pragma unroll
        for (int r = 0; r < 4; ++r) o[dt][r] *= av[r];
    }
    const float nm = -m_i * L2E;
#pragma unroll
    for (int c = 0; c < 8; ++c) pr[c] = exp2_fast(fmaf(pr[c], L2E, nm));
    float sm = pr[0];
#pragma unroll
    for (int c = 1; c < 8; ++c) sm += pr[c];
    sm += __shfl_xor(sm, 16, 64);
    sm += __shfl_xor(sm, 32, 64);
    l_i += sm;
    // P^T -> pw[q][k] (stride 40), two packed b64 writes; b128 A-frag read
    _Float16* pw = pb[w];
    half4 p0, p1;
#pragma unroll
    for (int r = 0; r < 4; ++r) {
      p0[r] = (_Float16)pr[r];
      p1[r] = (_Float16)pr[4 + r];
    }
    *(half4*)(pw + n16 * 40 + quad * 4) = p0;
    *(half4*)(pw + n16 * 40 + 16 + quad * 4) = p1;
    half8 pf = *(const half8*)(pw + n16 * 40 + quad * 8);
    const _Float16* vc = vb[buf];
    __builtin_amdgcn_s_setprio(1);
#pragma unroll
    for (int dt = 0; dt < 8; ++dt) {
      half8 vf = *(const half8*)&vc[dt * 512 + lane * 8];
      o[dt] = mfma16(pf, vf, o[dt]);
    }
    __builtin_amdgcn_s_setprio(0);
  };

  float4 ca[2], cb[2];
  // prologue: 2-deep pipeline (2*PP VMEM in flight)
  stage(0, 0);
  ldconn(0, ca);
  stage(1, 1);
  ldconn(1, cb);

#pragma unroll 1
  for (int t = 0; t < nt; t += 2) {
    // ---- phase t: buf0 / ca  (t+1 < nt always holds here) ----
    asm volatile("s_waitcnt vmcnt(%0)" ::"n"(PP));
    __builtin_amdgcn_sched_barrier(0);
    __builtin_amdgcn_s_barrier();
    __builtin_amdgcn_sched_barrier(0);
    compute(0, ca);
    if (t + 2 < nt) {
      __builtin_amdgcn_sched_barrier(0);
      __builtin_amdgcn_s_barrier();  // all waves done reading buf0
      stage(t + 2, 0);
      ldconn(t + 2, ca);
    }
    // ---- phase t+1: buf1 / cb ----
    if (t + 2 < nt) {
      asm volatile("s_waitcnt vmcnt(%0)" ::"n"(PP));
    } else {
      asm volatile("s_waitcnt vmcnt(0)");
    }
    __builtin_amdgcn_sched_barrier(0);
    __builtin_amdgcn_s_barrier();
    __builtin_amdgcn_sched_barrier(0);
    compute(1, cb);
    if (t + 3 < nt) {
      __builtin_amdgcn_sched_barrier(0);
      __builtin_amdgcn_s_barrier();  // all waves done reading buf1
      stage(t + 3, 1);
      ldconn(t + 3, cb);
    }
  }
  __builtin_amdgcn_sched_barrier(0);
  __builtin_amdgcn_s_barrier();  // protect scratch (kb/vb) reuse in epilogue

  // epilogue: transpose l via LDS broadcast, normalize, store A-frag order
  if (quad == 0) alb[w][n16] = l_i;
  const float4 lv = *(const float4*)&alb[w][quad * 4];
  float il[4];
#pragma unroll
  for (int r = 0; r < 4; ++r) il[r] = 1.f / lv[r];
  _Float16* tw = scratch;
#pragma unroll
  for (int dt = 0; dt < 8; ++dt)
#pragma unroll
    for (int r = 0; r < 4; ++r)
      tw[(quad * 4 + r) * 136 + dt * 16 + n16] = (_Float16)(o[dt][r] * il[r]);
  _Float16* ob = Og + ((size_t)(sk * 1024 + rt_g) * 4) * 512;
#pragma unroll
  for (int kc = 0; kc < 4; ++kc) {
    half8 of = *(const half8*)(tw + n16 * 136 + kc * 32 + quad * 8);
    *(half8*)(ob + kc * 512 + lane * 8) = of;
  }
  if (quad == 0)
    Ml[sk * 16384 + rt_g * 16 + n16] = make_float2(m_i, l_i);
}

// ---------------------------------------------------------------------------
// mlp: merge K-split partials -> swish -> @W1+b1 -> swish -> @W2+b2 -> LN
// ---------------------------------------------------------------------------
__global__ __launch_bounds__(256) void mlp_kernel(
    const _Float16* __restrict__ Og, const float2* __restrict__ Ml,
    const _Float16* __restrict__ Wf,
    const float* __restrict__ b1, const float* __restrict__ b2,
    const float* __restrict__ gamma, const float* __restrict__ beta,
    float* __restrict__ out, int nsplit) {
  __shared__ __align__(16) _Float16 hb[4][2176];
  const int tid = threadIdx.x, w = tid >> 6, lane = tid & 63;
  const int n16 = lane & 15, quad = lane >> 4;
  const int rt_g = blockIdx.x * 4 + w;

  // merge partials (per-lane: all this lane's elements are row n16 of rt_g)
  float2 ml[4];
  float m = -__builtin_inff();
  for (int s = 0; s < nsplit; ++s) {
    ml[s] = Ml[s * 16384 + rt_g * 16 + n16];
    m = fmaxf(m, ml[s].x);
  }
  float wgt[4], wsum = 0.f;
  for (int s = 0; s < nsplit; ++s) {
    wgt[s] = ml[s].y * exp2_fast((ml[s].x - m) * L2E);  // m raw-score domain
    wsum += wgt[s];
  }
  const float inv = 1.f / wsum;

  half8 hf[4];
#pragma unroll
  for (int kc = 0; kc < 4; ++kc) {
    float hv[8] = {0, 0, 0, 0, 0, 0, 0, 0};
    for (int s = 0; s < nsplit; ++s) {
      half8 ofr = *(const half8*)(Og +
          ((size_t)(s * 1024 + rt_g) * 4 + kc) * 512 + lane * 8);
#pragma unroll
      for (int j = 0; j < 8; ++j) hv[j] += wgt[s] * (float)ofr[j];
    }
    half8 h;
#pragma unroll
    for (int j = 0; j < 8; ++j) h[j] = (_Float16)swish_f(hv[j] * inv);
    hf[kc] = h;
  }

  float b1v[8], b2v[8], gv[8], bv[8];
#pragma unroll
  for (int ct = 0; ct < 8; ++ct) {
    b1v[ct] = b1[ct * 16 + n16];
    b2v[ct] = b2[ct * 16 + n16];
    gv[ct] = gamma[ct * 16 + n16];
    bv[ct] = beta[ct * 16 + n16];
  }

  f32x4 acc[8];
#pragma unroll
  for (int ct = 0; ct < 8; ++ct) acc[ct] = f32x4{0.f, 0.f, 0.f, 0.f};
#pragma unroll
  for (int ct = 0; ct < 8; ++ct)
#pragma unroll
    for (int kc = 0; kc < 4; ++kc) {
      half8 wf = *(const half8*)(Wf +
          ((size_t)(3 * 32 + ct * 4 + kc) * 64 + lane) * 8);
      acc[ct] = mfma16(hf[kc], wf, acc[ct]);
    }
  _Float16* hw = hb[w];
#pragma unroll
  for (int ct = 0; ct < 8; ++ct)
#pragma unroll
    for (int r = 0; r < 4; ++r)
      hw[(quad * 4 + r) * 136 + ct * 16 + n16] =
          (_Float16)swish_f(acc[ct][r] + b1v[ct]);
  half8 h1f[4];
#pragma unroll
  for (int kc = 0; kc < 4; ++kc)
    h1f[kc] = *(const half8*)(hw + n16 * 136 + kc * 32 + quad * 8);

#pragma unroll
  for (int ct = 0; ct < 8; ++ct) acc[ct] = f32x4{0.f, 0.f, 0.f, 0.f};
#pragma unroll
  for (int ct = 0; ct < 8; ++ct)
#pragma unroll
    for (int kc = 0; kc < 4; ++kc) {
      half8 wf = *(const half8*)(Wf +
          ((size_t)(4 * 32 + ct * 4 + kc) * 64 + lane) * 8);
      acc[ct] = mfma16(h1f[kc], wf, acc[ct]);
    }
  float hx[8][4];
  float sm[4] = {0, 0, 0, 0}, ss[4] = {0, 0, 0, 0};
#pragma unroll
  for (int ct = 0; ct < 8; ++ct)
#pragma unroll
    for (int r = 0; r < 4; ++r) {
      const float v = acc[ct][r] + b2v[ct];
      hx[ct][r] = v;
      sm[r] += v;
      ss[r] += v * v;
    }
#pragma unroll
  for (int r = 0; r < 4; ++r) {
    sm[r] = red16_sum(sm[r]);
    ss[r] = red16_sum(ss[r]);
  }
#pragma unroll
  for (int r = 0; r < 4; ++r) {
    const float mu = sm[r] * (1.f / 128.f);
    const float var = ss[r] * (1.f / 128.f) - mu * mu;
    const float rstd = rsqrtf(var + 1e-5f);
    const size_t row = (size_t)rt_g * 16 + quad * 4 + r;
#pragma unroll
    for (int ct = 0; ct < 8; ++ct)
      out[row * 128 + ct * 16 + n16] = (hx[ct][r] - mu) * rstd * gv[ct] + bv[ct];
  }
}

extern "C" void kernel_launch(void* const* d_in, const int* in_sizes, int n_in,
                              void* d_out, int out_size, void* d_ws,
                              size_t ws_size, hipStream_t stream) {
  const float* x     = (const float*)d_in[0];
  const float* conn  = (const float*)d_in[1];
  const float* Wq    = (const float*)d_in[2];
  const float* Wk    = (const float*)d_in[3];
  const float* Wv    = (const float*)d_in[4];
  const float* W1    = (const float*)d_in[5];
  const float* b1    = (const float*)d_in[6];
  const float* W2    = (const float*)d_in[7];
  const float* b2    = (const float*)d_in[8];
  const float* gamma = (const float*)d_in[9];
  const float* beta  = (const float*)d_in[10];
  float* out = (float*)d_out;

  // ws layout (f16 elems): Wf[81920] | Kg[2M] | Vg[2M] | Og[2M*nsplit] | Ml
  const size_t baseElems = (size_t)81920 + 2 * 2097152;  // Wf + Kg + Vg
  const size_t need4 =
      (baseElems + 4 * 2097152) * 2 + 4 * 16384 * sizeof(float2);
  const size_t need2 =
      (baseElems + 2 * 2097152) * 2 + 2 * 16384 * sizeof(float2);
  const int nsplit = (ws_size >= need4) ? 4 : (ws_size >= need2) ? 2 : 1;
  const int nt = 128 / nsplit;

  _Float16* Wf = (_Float16*)d_ws;
  _Float16* Kg = Wf + 81920;
  _Float16* Vg = Kg + 2097152;
  _Float16* Og = Vg + 2097152;
  float2* Ml = (float2*)(Og + (size_t)2097152 * nsplit);

  prep_kernel<<<40, 256, 0, stream>>>(Wq, Wk, Wv, W1, W2, Wf);
  kv_kernel<<<256, 256, 0, stream>>>(x, Wf, Kg, Vg);
  if (nsplit == 4) {
    flash_kernel<4><<<1024, 256, 0, stream>>>(x, conn, Wf, Kg, Vg, Og, Ml,
                                              nsplit, nt);
  } else if (nsplit == 2) {
    flash_kernel<2><<<1024, 128, 0, stream>>>(x, conn, Wf, Kg, Vg, Og, Ml,
                                              nsplit, nt);
  } else {
    flash_kernel<2><<<512, 128, 0, stream>>>(x, conn, Wf, Kg, Vg, Og, Ml,
                                             nsplit, nt);
  }
  mlp_kernel<<<256, 256, 0, stream>>>(Og, Ml, Wf, b1, b2, gamma, beta, out,
                                      nsplit);
}

// Round 3
// 438.875 us; speedup vs baseline: 1.0876x; 1.0876x over previous
//
#include <hip/hip_runtime.h>

#define L2E 1.44269504088896340736f
#define INV_SCALE 0.08838834764831845f  // 1/sqrt(128)

typedef _Float16 half8 __attribute__((ext_vector_type(8)));
typedef _Float16 half4 __attribute__((ext_vector_type(4)));
typedef float f32x4 __attribute__((ext_vector_type(4)));

__device__ __forceinline__ float exp2_fast(float x) {
#if __has_builtin(__builtin_amdgcn_exp2f)
  return __builtin_amdgcn_exp2f(x);
#else
  return exp2f(x);
#endif
}

__device__ __forceinline__ f32x4 mfma16(half8 a, half8 b, f32x4 c) {
  return __builtin_amdgcn_mfma_f32_16x16x32_f16(a, b, c, 0, 0, 0);
}

__device__ __forceinline__ void gload16(const void* g, void* l) {
  __builtin_amdgcn_global_load_lds(
      (const __attribute__((address_space(1))) void*)g,
      (__attribute__((address_space(3))) void*)l, 16, 0, 0);
}

__device__ __forceinline__ float swish_f(float v) {
  return v / (1.f + exp2_fast(-L2E * v));
}

template <int CTRL>
__device__ __forceinline__ float dppmov(float x) {
  int xi = __builtin_bit_cast(int, x);
  int r = __builtin_amdgcn_update_dpp(xi, xi, CTRL, 0xf, 0xf, false);
  return __builtin_bit_cast(float, r);
}
__device__ __forceinline__ float red16_sum(float x) {
  x += dppmov<0xB1>(x);
  x += dppmov<0x4E>(x);
  x += dppmov<0x141>(x);
  x += dppmov<0x140>(x);
  return x;
}

// ---------------------------------------------------------------------------
// prep: f16 B-fragment images of the 5 weight matrices.
// ---------------------------------------------------------------------------
__global__ __launch_bounds__(256) void prep_kernel(
    const float* __restrict__ Wq, const float* __restrict__ Wk,
    const float* __restrict__ Wv, const float* __restrict__ W1,
    const float* __restrict__ W2, _Float16* __restrict__ Wf) {
  const int g = blockIdx.x * 256 + threadIdx.x;  // [0, 10240)
  const int mat = g >> 11, rem = g & 2047;
  const int f = rem >> 6, lane = rem & 63;
  const int n = (f >> 2) * 16 + (lane & 15);
  const int k0 = (f & 3) * 32 + (lane >> 4) * 8;
  const float* W = (mat == 0) ? Wq : (mat == 1) ? Wk : (mat == 2) ? Wv
                   : (mat == 3) ? W1 : W2;
  half8 h;
#pragma unroll
  for (int j = 0; j < 8; ++j) h[j] = (_Float16)W[(k0 + j) * 128 + n];
  *(half8*)(Wf + (size_t)g * 8) = h;
}

// ---------------------------------------------------------------------------
// kv: K/V projections into MFMA-fragment-ordered global images.
// ---------------------------------------------------------------------------
__global__ __launch_bounds__(256) void kv_kernel(
    const float* __restrict__ x, const _Float16* __restrict__ Wf,
    _Float16* __restrict__ Kg, _Float16* __restrict__ Vg) {
  __shared__ __align__(16) _Float16 sc[64 * 136];
  const int tid = threadIdx.x;
  const int w = tid >> 6, lane = tid & 63;
  const int n16 = lane & 15, quad = lane >> 4;
  const int blk = blockIdx.x;  // 64 rows/block

  half8 xf[4];
  {
    const float* xr = x + (size_t)(blk * 64 + w * 16 + n16) * 128 + quad * 8;
#pragma unroll
    for (int kc = 0; kc < 4; ++kc) {
      float4 a = *(const float4*)(xr + kc * 32);
      float4 b = *(const float4*)(xr + kc * 32 + 4);
      half8 h;
      h[0] = (_Float16)a.x; h[1] = (_Float16)a.y;
      h[2] = (_Float16)a.z; h[3] = (_Float16)a.w;
      h[4] = (_Float16)b.x; h[5] = (_Float16)b.y;
      h[6] = (_Float16)b.z; h[7] = (_Float16)b.w;
      xf[kc] = h;
    }
  }

  for (int mat = 0; mat < 2; ++mat) {  // 0 -> Wk image(1), 1 -> Wv image(2)
    f32x4 acc[8];
#pragma unroll
    for (int ct = 0; ct < 8; ++ct) acc[ct] = f32x4{0.f, 0.f, 0.f, 0.f};
#pragma unroll
    for (int ct = 0; ct < 8; ++ct)
#pragma unroll
      for (int kc = 0; kc < 4; ++kc) {
        half8 wf = *(const half8*)(Wf +
            ((size_t)((mat + 1) * 32 + ct * 4 + kc) * 64 + lane) * 8);
        acc[ct] = mfma16(xf[kc], wf, acc[ct]);
      }
#pragma unroll
    for (int ct = 0; ct < 8; ++ct)
#pragma unroll
      for (int r = 0; r < 4; ++r)
        sc[(w * 16 + quad * 4 + r) * 136 + ct * 16 + n16] = (_Float16)acc[ct][r];
    __syncthreads();

    if (mat == 0) {  // K
#pragma unroll
      for (int i = 0; i < 4; ++i) {
        const int c = tid + 256 * i;
        const int ln = c & 63, kc = (c >> 6) & 3, ct = (c >> 8) & 1, tl = (c >> 9) & 1;
        half8 v = *(const half8*)&sc[(tl * 32 + ct * 16 + (ln & 15)) * 136 +
                                     kc * 32 + (ln >> 4) * 8];
        *(half8*)(Kg + ((((size_t)(blk * 2 + tl)) * 2 + ct) * 4 + kc) * 512 + ln * 8) = v;
      }
    } else {  // V transposed fragments
#pragma unroll
      for (int i = 0; i < 4; ++i) {
        const int c = tid + 256 * i;
        const int ln = c & 63, dt = (c >> 6) & 7, tl = (c >> 9) & 1;
        const int q2 = ln >> 4, nn = ln & 15;
        half8 v;
#pragma unroll
        for (int j = 0; j < 8; ++j)
          v[j] = sc[(tl * 32 + q2 * 8 + j) * 136 + dt * 16 + nn];
        *(half8*)(Vg + (((size_t)(blk * 2 + tl)) * 8 + dt) * 512 + ln * 8) = v;
      }
    }
    __syncthreads();
  }
}

// ---------------------------------------------------------------------------
// flash: S^T = K.Q^T layout, online softmax in registers.
//
// R3 change: conn reads batched in groups of 4 K-tiles (8x float4 per lane,
// 512B per q-row issued back-to-back) so the DRAM controller sees 4x longer
// same-row burst trains. Theory: flash is pinned at ~1 TB/s by DRAM
// row-miss-per-128B-request behavior of the 16-rows-strided conn pattern
// (R1: waves null; R2: vmcnt depth null -> MC-throughput-bound, not latency).
// K/V staging + 2-barrier counted-vmcnt phase structure unchanged from R2.
// ---------------------------------------------------------------------------
template <int NW>
__global__ __launch_bounds__(NW * 64, 3) void flash_kernel(
    const float* __restrict__ x, const float* __restrict__ conn,
    const _Float16* __restrict__ Wf,
    const _Float16* __restrict__ Kg, const _Float16* __restrict__ Vg,
    _Float16* __restrict__ Og, float2* __restrict__ Ml,
    int nsplit, int nt) {
  __shared__ __align__(16) _Float16 kb[2][4096];
  __shared__ __align__(16) _Float16 vb[2][4096];
  __shared__ __align__(16) _Float16 pb[NW][656];
  __shared__ __align__(16) float alb[NW][16];

  const int tid = threadIdx.x, w = tid >> 6, lane = tid & 63;
  const int n16 = lane & 15, quad = lane >> 4;
  const int bid = blockIdx.x;
  int batch, sk, rg;
  if (nsplit == 4) {
    batch = bid & 3; sk = (bid >> 2) & 3; rg = bid >> 4;
  } else if (nsplit == 2) {
    batch = bid & 3; sk = (bid >> 2) & 1; rg = bid >> 3;
  } else {
    batch = bid & 3; sk = 0; rg = bid >> 2;
  }
  const int rt_g = batch * 256 + rg * NW + w;
  const int t0 = sk * nt;
  const int rowb = rg * (NW * 16) + w * 16 + n16;  // q-row within batch

  // per-wave private scratch region (2176 f16 needed, buffers are 4096)
  _Float16* scratch = (w < 2) ? &kb[w][0] : &vb[w - 2][0];

  // ---- Q = x @ Wq for this wave's 16 rows (once); scratch in kb/vb ----
  half8 qf[4];
  {
    half8 xf[4];
    const float* xr = x + ((size_t)batch * 4096 + rowb) * 128 + quad * 8;
#pragma unroll
    for (int kc = 0; kc < 4; ++kc) {
      float4 a = *(const float4*)(xr + kc * 32);
      float4 b = *(const float4*)(xr + kc * 32 + 4);
      half8 h;
      h[0] = (_Float16)a.x; h[1] = (_Float16)a.y;
      h[2] = (_Float16)a.z; h[3] = (_Float16)a.w;
      h[4] = (_Float16)b.x; h[5] = (_Float16)b.y;
      h[6] = (_Float16)b.z; h[7] = (_Float16)b.w;
      xf[kc] = h;
    }
    _Float16* tw = scratch;
#pragma unroll
    for (int ct = 0; ct < 8; ++ct) {
      f32x4 aq = f32x4{0.f, 0.f, 0.f, 0.f};
#pragma unroll
      for (int kc = 0; kc < 4; ++kc) {
        half8 wf = *(const half8*)(Wf + ((size_t)(ct * 4 + kc) * 64 + lane) * 8);
        aq = mfma16(xf[kc], wf, aq);
      }
#pragma unroll
      for (int r = 0; r < 4; ++r)
        tw[(quad * 4 + r) * 136 + ct * 16 + n16] = (_Float16)aq[r];
    }
#pragma unroll
    for (int kc = 0; kc < 4; ++kc)
      qf[kc] = *(const half8*)(tw + n16 * 136 + kc * 32 + quad * 8);
  }
  __syncthreads();  // scratch reads drained; kb/vb free for staging

  const _Float16* kp = Kg + (size_t)batch * 524288 + (size_t)t0 * 4096 + tid * 8;
  const _Float16* vp = Vg + (size_t)batch * 524288 + (size_t)t0 * 4096 + tid * 8;
  const float* cp = conn + (size_t)batch * 16777216 + (size_t)rowb * 4096 +
                    (size_t)t0 * 32 + quad * 4;
  const int wbase = (tid & ~63) * 8;
  constexpr int NC = 8 / NW;   // gload16 per matrix per thread
  constexpr int ST = 2 * NC;   // stage VMEM instrs per phase (K+V)
  constexpr int W_HI = ST + 8; // wait at p=0,1 (stage(t+1) + group conn burst)
  constexpr int W_LO = ST;     // wait at p=2,3 (stage(t+1) only)

  auto stage = [&](int t, int buf) {
    const _Float16* ks = kp + (size_t)t * 4096;
    const _Float16* vs = vp + (size_t)t * 4096;
#pragma unroll
    for (int c = 0; c < NC; ++c) {
      gload16(ks + c * (NW * 512), &kb[buf][c * (NW * 512) + wbase]);
      gload16(vs + c * (NW * 512), &vb[buf][c * (NW * 512) + wbase]);
    }
  };
  // one conn group = 4 K-tiles = 512B per q-row, 8 chunks issued back-to-back
  auto ldconn_group = [&](int g, float4* cr) {
    const float* c0 = cp + (size_t)g * 128;
#pragma unroll
    for (int j = 0; j < 8; ++j) cr[j] = *(const float4*)(c0 + j * 16);
  };

  f32x4 o[8];
#pragma unroll
  for (int dt = 0; dt < 8; ++dt) o[dt] = f32x4{0.f, 0.f, 0.f, 0.f};
  float m_i = -__builtin_inff();
  float l_i = 0.f;

  auto compute = [&](int buf, const float4* cc) {
    f32x4 s0 = f32x4{0.f, 0.f, 0.f, 0.f};
    f32x4 s1 = f32x4{0.f, 0.f, 0.f, 0.f};
    const _Float16* kc_ = kb[buf];
    __builtin_amdgcn_s_setprio(1);
#pragma unroll
    for (int kc = 0; kc < 4; ++kc) {
      half8 kf0 = *(const half8*)&kc_[kc * 512 + lane * 8];
      half8 kf1 = *(const half8*)&kc_[(4 + kc) * 512 + lane * 8];
      s0 = mfma16(kf0, qf[kc], s0);  // S^T: A=K, B=Q
      s1 = mfma16(kf1, qf[kc], s1);
    }
    __builtin_amdgcn_s_setprio(0);
    float pr[8];
#pragma unroll
    for (int r = 0; r < 4; ++r) {
      pr[r] = fmaf(s0[r], INV_SCALE, cc[0][r]);
      pr[4 + r] = fmaf(s1[r], INV_SCALE, cc[1][r]);
    }
    float mx = pr[0];
#pragma unroll
    for (int c = 1; c < 8; ++c) mx = fmaxf(mx, pr[c]);
    mx = fmaxf(mx, __shfl_xor(mx, 16, 64));
    mx = fmaxf(mx, __shfl_xor(mx, 32, 64));
    if (__any(mx > m_i)) {
      const float mn = fmaxf(m_i, mx);
      const float al = exp2_fast((m_i - mn) * L2E);
      m_i = mn;
      l_i *= al;
      if (quad == 0) alb[w][n16] = al;
      const float4 av = *(const float4*)&alb[w][quad * 4];
#pragma unroll
      for (int dt = 0; dt < 8; ++dt)
#pragma unroll
        for (int r = 0; r < 4; ++r) o[dt][r] *= av[r];
    }
    const float nm = -m_i * L2E;
#pragma unroll
    for (int c = 0; c < 8; ++c) pr[c] = exp2_fast(fmaf(pr[c], L2E, nm));
    float sm = pr[0];
#pragma unroll
    for (int c = 1; c < 8; ++c) sm += pr[c];
    sm += __shfl_xor(sm, 16, 64);
    sm += __shfl_xor(sm, 32, 64);
    l_i += sm;
    // P^T -> pw[q][k] (stride 40), two packed b64 writes; b128 A-frag read
    _Float16* pw = pb[w];
    half4 p0, p1;
#pragma unroll
    for (int r = 0; r < 4; ++r) {
      p0[r] = (_Float16)pr[r];
      p1[r] = (_Float16)pr[4 + r];
    }
    *(half4*)(pw + n16 * 40 + quad * 4) = p0;
    *(half4*)(pw + n16 * 40 + 16 + quad * 4) = p1;
    half8 pf = *(const half8*)(pw + n16 * 40 + quad * 8);
    const _Float16* vc = vb[buf];
    __builtin_amdgcn_s_setprio(1);
#pragma unroll
    for (int dt = 0; dt < 8; ++dt) {
      half8 vf = *(const half8*)&vc[dt * 512 + lane * 8];
      o[dt] = mfma16(pf, vf, o[dt]);
    }
    __builtin_amdgcn_s_setprio(0);
  };

  const int NG = nt >> 2;  // conn groups of 4 tiles; NG is even (8/16/32)
  float4 cA[8], cB[8];

  // prologue (order matters for vmcnt accounting):
  ldconn_group(0, cA);  // 8
  stage(0, 0);          // ST
  stage(1, 1);          // ST
  ldconn_group(1, cB);  // 8

  // phase p of a group: wait(p<2 ? W_HI : W_LO), barrier, compute,
  // barrier, stage(t+2). conn refill for group g+2 at group end.
  auto group_body = [&](int g, float4* C) {
    const int tb = g * 4;
#pragma unroll
    for (int p = 0; p < 4; ++p) {
      if (p < 2) {
        asm volatile("s_waitcnt vmcnt(%0)" ::"n"(W_HI));
      } else {
        asm volatile("s_waitcnt vmcnt(%0)" ::"n"(W_LO));
      }
      __builtin_amdgcn_sched_barrier(0);
      __builtin_amdgcn_s_barrier();
      __builtin_amdgcn_sched_barrier(0);
      compute(p & 1, &C[2 * p]);
      __builtin_amdgcn_sched_barrier(0);
      __builtin_amdgcn_s_barrier();
      __builtin_amdgcn_sched_barrier(0);
      stage(tb + p + 2, p & 1);
      __builtin_amdgcn_sched_barrier(0);
    }
    if (g + 2 < NG) ldconn_group(g + 2, C);
    __builtin_amdgcn_sched_barrier(0);
  };

#pragma unroll 1
  for (int g = 0; g + 3 < NG; g += 2) {
    group_body(g, cA);
    group_body(g + 1, cB);
  }
  group_body(NG - 2, cA);  // no refill (guard inside)

  {  // last group (NG-1, conn in cB): waits {ST,ST,ST,0}; stage only p<2
#pragma unroll
    for (int p = 0; p < 4; ++p) {
      if (p < 3) {
        asm volatile("s_waitcnt vmcnt(%0)" ::"n"(W_LO));
      } else {
        asm volatile("s_waitcnt vmcnt(0)");
      }
      __builtin_amdgcn_sched_barrier(0);
      __builtin_amdgcn_s_barrier();
      __builtin_amdgcn_sched_barrier(0);
      compute(p & 1, &cB[2 * p]);
      __builtin_amdgcn_sched_barrier(0);
      __builtin_amdgcn_s_barrier();
      __builtin_amdgcn_sched_barrier(0);
      if (p < 2) {
        stage((NG - 1) * 4 + p + 2, p & 1);
        __builtin_amdgcn_sched_barrier(0);
      }
    }
  }

  // epilogue: transpose l via LDS broadcast, normalize, store A-frag order
  if (quad == 0) alb[w][n16] = l_i;
  const float4 lv = *(const float4*)&alb[w][quad * 4];
  float il[4];
#pragma unroll
  for (int r = 0; r < 4; ++r) il[r] = 1.f / lv[r];
  _Float16* tw = scratch;
#pragma unroll
  for (int dt = 0; dt < 8; ++dt)
#pragma unroll
    for (int r = 0; r < 4; ++r)
      tw[(quad * 4 + r) * 136 + dt * 16 + n16] = (_Float16)(o[dt][r] * il[r]);
  _Float16* ob = Og + ((size_t)(sk * 1024 + rt_g) * 4) * 512;
#pragma unroll
  for (int kc = 0; kc < 4; ++kc) {
    half8 of = *(const half8*)(tw + n16 * 136 + kc * 32 + quad * 8);
    *(half8*)(ob + kc * 512 + lane * 8) = of;
  }
  if (quad == 0)
    Ml[sk * 16384 + rt_g * 16 + n16] = make_float2(m_i, l_i);
}

// ---------------------------------------------------------------------------
// mlp: merge K-split partials -> swish -> @W1+b1 -> swish -> @W2+b2 -> LN
// ---------------------------------------------------------------------------
__global__ __launch_bounds__(256) void mlp_kernel(
    const _Float16* __restrict__ Og, const float2* __restrict__ Ml,
    const _Float16* __restrict__ Wf,
    const float* __restrict__ b1, const float* __restrict__ b2,
    const float* __restrict__ gamma, const float* __restrict__ beta,
    float* __restrict__ out, int nsplit) {
  __shared__ __align__(16) _Float16 hb[4][2176];
  const int tid = threadIdx.x, w = tid >> 6, lane = tid & 63;
  const int n16 = lane & 15, quad = lane >> 4;
  const int rt_g = blockIdx.x * 4 + w;

  // merge partials (per-lane: all this lane's elements are row n16 of rt_g)
  float2 ml[4];
  float m = -__builtin_inff();
  for (int s = 0; s < nsplit; ++s) {
    ml[s] = Ml[s * 16384 + rt_g * 16 + n16];
    m = fmaxf(m, ml[s].x);
  }
  float wgt[4], wsum = 0.f;
  for (int s = 0; s < nsplit; ++s) {
    wgt[s] = ml[s].y * exp2_fast((ml[s].x - m) * L2E);  // m raw-score domain
    wsum += wgt[s];
  }
  const float inv = 1.f / wsum;

  half8 hf[4];
#pragma unroll
  for (int kc = 0; kc < 4; ++kc) {
    float hv[8] = {0, 0, 0, 0, 0, 0, 0, 0};
    for (int s = 0; s < nsplit; ++s) {
      half8 ofr = *(const half8*)(Og +
          ((size_t)(s * 1024 + rt_g) * 4 + kc) * 512 + lane * 8);
#pragma unroll
      for (int j = 0; j < 8; ++j) hv[j] += wgt[s] * (float)ofr[j];
    }
    half8 h;
#pragma unroll
    for (int j = 0; j < 8; ++j) h[j] = (_Float16)swish_f(hv[j] * inv);
    hf[kc] = h;
  }

  float b1v[8], b2v[8], gv[8], bv[8];
#pragma unroll
  for (int ct = 0; ct < 8; ++ct) {
    b1v[ct] = b1[ct * 16 + n16];
    b2v[ct] = b2[ct * 16 + n16];
    gv[ct] = gamma[ct * 16 + n16];
    bv[ct] = beta[ct * 16 + n16];
  }

  f32x4 acc[8];
#pragma unroll
  for (int ct = 0; ct < 8; ++ct) acc[ct] = f32x4{0.f, 0.f, 0.f, 0.f};
#pragma unroll
  for (int ct = 0; ct < 8; ++ct)
#pragma unroll
    for (int kc = 0; kc < 4; ++kc) {
      half8 wf = *(const half8*)(Wf +
          ((size_t)(3 * 32 + ct * 4 + kc) * 64 + lane) * 8);
      acc[ct] = mfma16(hf[kc], wf, acc[ct]);
    }
  _Float16* hw = hb[w];
#pragma unroll
  for (int ct = 0; ct < 8; ++ct)
#pragma unroll
    for (int r = 0; r < 4; ++r)
      hw[(quad * 4 + r) * 136 + ct * 16 + n16] =
          (_Float16)swish_f(acc[ct][r] + b1v[ct]);
  half8 h1f[4];
#pragma unroll
  for (int kc = 0; kc < 4; ++kc)
    h1f[kc] = *(const half8*)(hw + n16 * 136 + kc * 32 + quad * 8);

#pragma unroll
  for (int ct = 0; ct < 8; ++ct) acc[ct] = f32x4{0.f, 0.f, 0.f, 0.f};
#pragma unroll
  for (int ct = 0; ct < 8; ++ct)
#pragma unroll
    for (int kc = 0; kc < 4; ++kc) {
      half8 wf = *(const half8*)(Wf +
          ((size_t)(4 * 32 + ct * 4 + kc) * 64 + lane) * 8);
      acc[ct] = mfma16(h1f[kc], wf, acc[ct]);
    }
  float hx[8][4];
  float sm[4] = {0, 0, 0, 0}, ss[4] = {0, 0, 0, 0};
#pragma unroll
  for (int ct = 0; ct < 8; ++ct)
#pragma unroll
    for (int r = 0; r < 4; ++r) {
      const float v = acc[ct][r] + b2v[ct];
      hx[ct][r] = v;
      sm[r] += v;
      ss[r] += v * v;
    }
#pragma unroll
  for (int r = 0; r < 4; ++r) {
    sm[r] = red16_sum(sm[r]);
    ss[r] = red16_sum(ss[r]);
  }
#pragma unroll
  for (int r = 0; r < 4; ++r) {
    const float mu = sm[r] * (1.f / 128.f);
    const float var = ss[r] * (1.f / 128.f) - mu * mu;
    const float rstd = rsqrtf(var + 1e-5f);
    const size_t row = (size_t)rt_g * 16 + quad * 4 + r;
#pragma unroll
    for (int ct = 0; ct < 8; ++ct)
      out[row * 128 + ct * 16 + n16] = (hx[ct][r] - mu) * rstd * gv[ct] + bv[ct];
  }
}

extern "C" void kernel_launch(void* const* d_in, const int* in_sizes, int n_in,
                              void* d_out, int out_size, void* d_ws,
                              size_t ws_size, hipStream_t stream) {
  const float* x     = (const float*)d_in[0];
  const float* conn  = (const float*)d_in[1];
  const float* Wq    = (const float*)d_in[2];
  const float* Wk    = (const float*)d_in[3];
  const float* Wv    = (const float*)d_in[4];
  const float* W1    = (const float*)d_in[5];
  const float* b1    = (const float*)d_in[6];
  const float* W2    = (const float*)d_in[7];
  const float* b2    = (const float*)d_in[8];
  const float* gamma = (const float*)d_in[9];
  const float* beta  = (const float*)d_in[10];
  float* out = (float*)d_out;

  // ws layout (f16 elems): Wf[81920] | Kg[2M] | Vg[2M] | Og[2M*nsplit] | Ml
  const size_t baseElems = (size_t)81920 + 2 * 2097152;  // Wf + Kg + Vg
  const size_t need4 =
      (baseElems + 4 * 2097152) * 2 + 4 * 16384 * sizeof(float2);
  const size_t need2 =
      (baseElems + 2 * 2097152) * 2 + 2 * 16384 * sizeof(float2);
  const int nsplit = (ws_size >= need4) ? 4 : (ws_size >= need2) ? 2 : 1;
  const int nt = 128 / nsplit;

  _Float16* Wf = (_Float16*)d_ws;
  _Float16* Kg = Wf + 81920;
  _Float16* Vg = Kg + 2097152;
  _Float16* Og = Vg + 2097152;
  float2* Ml = (float2*)(Og + (size_t)2097152 * nsplit);

  prep_kernel<<<40, 256, 0, stream>>>(Wq, Wk, Wv, W1, W2, Wf);
  kv_kernel<<<256, 256, 0, stream>>>(x, Wf, Kg, Vg);
  if (nsplit == 4) {
    flash_kernel<4><<<1024, 256, 0, stream>>>(x, conn, Wf, Kg, Vg, Og, Ml,
                                              nsplit, nt);
  } else if (nsplit == 2) {
    flash_kernel<2><<<1024, 128, 0, stream>>>(x, conn, Wf, Kg, Vg, Og, Ml,
                                              nsplit, nt);
  } else {
    flash_kernel<2><<<512, 128, 0, stream>>>(x, conn, Wf, Kg, Vg, Og, Ml,
                                             nsplit, nt);
  }
  mlp_kernel<<<256, 256, 0, stream>>>(Og, Ml, Wf, b1, b2, gamma, beta, out,
                                      nsplit);
}